// Round 9
// baseline (4267.724 us; speedup 1.0000x reference)
//
#include <hip/hip_runtime.h>
#include <hip/hip_bf16.h>

typedef unsigned short ushort_t;
typedef short bf16x8 __attribute__((ext_vector_type(8)));
typedef unsigned short us16x8 __attribute__((ext_vector_type(8)));
typedef float f32x4  __attribute__((ext_vector_type(4)));

#define BATCH   2
#define FRAMES  8
#define GRID_   14
#define NTOK    196
#define PS      16
#define IMG     224
#define L_SEQ   1568
#define DM      384
#define DI      768
#define DTR     24
#define DS      16
#define DEPTH   24
#define KCONV   4
#define NROWS   (BATCH*L_SEQ)   // 3136
#define EPS_    1e-5f
#define NCHUNK  49              // 49*32 = 1568
#define CLEN    32
#define DTILE   64
#define NDC     (DI/DTILE)      // 12
#define LOG2E   1.4426950408889634f

__device__ __forceinline__ ushort_t f2us(float f){
    __hip_bfloat16 h = __float2bfloat16(f);
    return *reinterpret_cast<ushort_t*>(&h);
}
__device__ __forceinline__ float us2f(ushort_t u){
    return __uint_as_float(((unsigned int)u) << 16);
}
__device__ __forceinline__ ushort4 f4tous4(float4 v){
    ushort4 o;
    o.x = f2us(v.x); o.y = f2us(v.y); o.z = f2us(v.z); o.w = f2us(v.w);
    return o;
}

// ---------------- patchify (4 px per thread, float4 read) -------------------------
__global__ __launch_bounds__(256) void patchify_kernel(const float* __restrict__ x,
                                                       ushort_t* __restrict__ patches){
    int idx4 = blockIdx.x*256 + threadIdx.x;
    if (idx4 >= NROWS*768/4) return;
    int idx = idx4*4;
    int k   = idx % 768;
    int r   = idx / 768;
    int tok = r % NTOK;
    int bt  = r / NTOK;
    int t = bt % FRAMES, b = bt / FRAMES;
    int gy = tok / GRID_, gx = tok % GRID_;
    int c = k / 256; int rem = k % 256; int py = rem/16, px = rem%16; // px 4-aligned
    long xo = (((long)(b*3 + c)*FRAMES + t)*IMG + (gy*PS+py))*IMG + (gx*PS+px);
    float4 v = *(const float4*)(x + xo);
    *(ushort4*)(patches + idx) = f4tous4(v);
}

__global__ __launch_bounds__(256) void convert_kernel(const float* __restrict__ in,
                                                      ushort_t* __restrict__ out, int n){
    int i = blockIdx.x*256 + threadIdx.x;
    if (i < n) out[i] = f2us(in[i]);
}

// ---------------- grouped weight conversion (4-wide, norm_w folded into wi) -------
#define WI_SZ  (2*DI*DM)
#define WO_SZ  (DM*DI)
#define WX_SZ  (56*DI)
#define WDT_SZ (DI*32)
#define WCVT_TOTAL (WI_SZ + WO_SZ + 2*WX_SZ + 2*WDT_SZ)   // 1,019,904
#define WCVT_Q  (WCVT_TOTAL/4)                            // 254,976

__global__ __launch_bounds__(256) void convert_group_kernel(
        const float* __restrict__ wi, const float* __restrict__ wo,
        const float* __restrict__ wxf, const float* __restrict__ wxb,
        const float* __restrict__ wdtf, const float* __restrict__ wdtb,
        const float* __restrict__ nw,
        ushort_t* __restrict__ out, int l0, int count)
{
    long gid = (long)blockIdx.x*256 + threadIdx.x;
    if (gid >= (long)count*WCVT_Q) return;
    int ly = (int)(gid / WCVT_Q);
    int r  = (int)(gid % WCVT_Q)*4;
    int l  = l0 + ly;
    float4 v;
    if (r < WI_SZ){
        v = *(const float4*)(wi + (long)l*WI_SZ + r);
        int c = r % DM;                       // DM%4==0 -> no row crossing
        float4 wv = *(const float4*)(nw + (long)l*DM + c);
        v.x *= wv.x; v.y *= wv.y; v.z *= wv.z; v.w *= wv.w;
    }
    else if (r < WI_SZ+WO_SZ)            v = *(const float4*)(wo + (long)l*WO_SZ + r - WI_SZ);
    else if (r < WI_SZ+WO_SZ+WX_SZ)      v = *(const float4*)(wxf + (long)l*WX_SZ + r - WI_SZ - WO_SZ);
    else if (r < WI_SZ+WO_SZ+2*WX_SZ)    v = *(const float4*)(wxb + (long)l*WX_SZ + r - WI_SZ - WO_SZ - WX_SZ);
    else if (r < WI_SZ+WO_SZ+2*WX_SZ+WDT_SZ){
        int i = r - (WI_SZ+WO_SZ+2*WX_SZ);
        int rr = i >> 5, c = i & 31;           // c 4-aligned; pad boundary 24 is 4-aligned
        v = (c < DTR) ? *(const float4*)(wdtf + (long)l*DI*DTR + rr*DTR + c)
                      : float4{0.f,0.f,0.f,0.f};
    } else {
        int i = r - (WI_SZ+WO_SZ+2*WX_SZ+WDT_SZ);
        int rr = i >> 5, c = i & 31;
        v = (c < DTR) ? *(const float4*)(wdtb + (long)l*DI*DTR + rr*DTR + c)
                      : float4{0.f,0.f,0.f,0.f};
    }
    *(ushort4*)(out + (long)ly*WCVT_TOTAL + r) = f4tous4(v);
}

// ---------------- MFMA GEMM: C[M,N] = A[M,K] * W[N,K]^T --------------------------
// STAGE=1: A-tile staged through double-buffered LDS (shared by 4 waves).
// NORM=1: A is f32 (residual); stager computes per-row rsqrt(mean(x^2)+eps) and
//         the epilogue multiplies by it (norm_w is pre-folded into W).
// modes: 0 out_proj -> res +=; 1 in_proj split -> bf16 xi/zi; 2 patch -> res=v+aux;
//        3 dt softplus+bias(z) -> bf16; 4 xproj dual (f32 56 + bf16 32 pad0)
template<int MT, int STAGE, int NORM>
__global__ __launch_bounds__(256) void gemm_mfma_kernel(
        const void* __restrict__ Av_, int lda, long strideA,
        const ushort_t* __restrict__ W, int ldw, long strideW,
        int K, int N,
        float* __restrict__ out0, long strideO0,
        ushort_t* __restrict__ outb0, ushort_t* __restrict__ outb1, long strideOb,
        int mode,
        const float* __restrict__ aux0, const float* __restrict__ aux1,
        const float* __restrict__ aux2)
{
    int z = blockIdx.z;
    W += (long)z * strideW;
    if (out0)  out0  += (long)z * strideO0;
    if (outb0) outb0 += (long)z * strideOb;

    int tid  = threadIdx.x;
    int wave = tid >> 6, lane = tid & 63;
    int l15 = lane & 15, quad = lane >> 4;
    int m0 = blockIdx.y * (MT*16), n0 = blockIdx.x * 64;

    const ushort_t* wp = W + (long)(n0 + wave*16 + l15)*ldw + quad*8;

    f32x4 acc[MT];
    #pragma unroll
    for (int mt = 0; mt < MT; mt++) acc[mt] = f32x4{0,0,0,0};

    __shared__ float sscale[MT*16];

    if constexpr (STAGE){
        __shared__ alignas(16) ushort_t As[2][MT*16][40];
        bool act = (tid < MT*64);
        int srow = tid >> 2, skq = tid & 3;
        int nIter = K >> 5;
        float ss = 0.f;
        us16x8 av = {};
        const ushort_t* ag = nullptr;
        const float*    agf = nullptr;
        if constexpr (NORM){
            agf = (const float*)Av_ + (long)z*strideA + (long)(m0 + srow)*lda + skq*8;
            float4 a0 = *(const float4*)agf;
            float4 a1 = *(const float4*)(agf + 4);
            ss += a0.x*a0.x + a0.y*a0.y + a0.z*a0.z + a0.w*a0.w
                + a1.x*a1.x + a1.y*a1.y + a1.z*a1.z + a1.w*a1.w;
            av[0]=(short)f2us(a0.x); av[1]=(short)f2us(a0.y); av[2]=(short)f2us(a0.z); av[3]=(short)f2us(a0.w);
            av[4]=(short)f2us(a1.x); av[5]=(short)f2us(a1.y); av[6]=(short)f2us(a1.z); av[7]=(short)f2us(a1.w);
        } else {
            ag = (const ushort_t*)Av_ + (long)z*strideA + (long)(m0 + srow)*lda + skq*8;
            if (act) av = *(const us16x8*)ag;
        }
        for (int it = 0; it < nIter; it++){
            if (act) *(us16x8*)&As[it&1][srow][skq*8] = av;
            if (it+1 < nIter){
                if constexpr (NORM){
                    float4 a0 = *(const float4*)(agf + (long)(it+1)*32);
                    float4 a1 = *(const float4*)(agf + (long)(it+1)*32 + 4);
                    ss += a0.x*a0.x + a0.y*a0.y + a0.z*a0.z + a0.w*a0.w
                        + a1.x*a1.x + a1.y*a1.y + a1.z*a1.z + a1.w*a1.w;
                    av[0]=(short)f2us(a0.x); av[1]=(short)f2us(a0.y); av[2]=(short)f2us(a0.z); av[3]=(short)f2us(a0.w);
                    av[4]=(short)f2us(a1.x); av[5]=(short)f2us(a1.y); av[6]=(short)f2us(a1.z); av[7]=(short)f2us(a1.w);
                } else {
                    if (act) av = *(const us16x8*)(ag + (long)(it+1)*32);
                }
            }
            __syncthreads();
            bf16x8 bfrag = *reinterpret_cast<const bf16x8*>(wp + it*32);
            #pragma unroll
            for (int mt = 0; mt < MT; mt++){
                bf16x8 afrag = *reinterpret_cast<const bf16x8*>(&As[it&1][mt*16+l15][quad*8]);
                acc[mt] = __builtin_amdgcn_mfma_f32_16x16x32_bf16(afrag, bfrag, acc[mt], 0, 0, 0);
            }
        }
        if constexpr (NORM){
            ss += __shfl_xor(ss, 1);
            ss += __shfl_xor(ss, 2);
            if (skq == 0) sscale[srow] = rsqrtf(ss/(float)K + EPS_);
            __syncthreads();
        }
    } else {
        const ushort_t* ap0 = (const ushort_t*)Av_ + (long)z*strideA + (long)(m0 + l15)*lda + quad*8;
        for (int k0 = 0; k0 < K; k0 += 32){
            bf16x8 bfrag = *reinterpret_cast<const bf16x8*>(wp + k0);
            #pragma unroll
            for (int mt = 0; mt < MT; mt++){
                bf16x8 afrag = *reinterpret_cast<const bf16x8*>(ap0 + (long)mt*16*lda + k0);
                acc[mt] = __builtin_amdgcn_mfma_f32_16x16x32_bf16(afrag, bfrag, acc[mt], 0, 0, 0);
            }
        }
    }

    int cn = n0 + wave*16 + l15;
    #pragma unroll
    for (int mt = 0; mt < MT; mt++){
        #pragma unroll
        for (int r = 0; r < 4; r++){
            int lrow = mt*16 + quad*4 + r;
            int row = m0 + lrow;
            float v = acc[mt][r];
            if constexpr (NORM){ v *= sscale[lrow]; }
            if (mode == 0){
                out0[(long)row*N + cn] += v;
            } else if (mode == 1){
                if (cn < DI) outb0[(long)row*DI + cn] = f2us(v);
                else         outb1[(long)row*DI + cn - DI] = f2us(v);
            } else if (mode == 2){
                int tok = row % NTOK, t = (row/NTOK) % FRAMES;
                out0[(long)row*N + cn] = v + aux0[cn] + aux1[tok*DM+cn] + aux2[t*DM+cn];
            } else if (mode == 3){
                const float* bias = z ? aux1 : aux0;
                float xs = v + bias[cn];
                float sp = (xs > 20.f) ? xs : log1pf(__expf(xs));
                outb0[(long)row*N + cn] = f2us(sp);
            } else { // mode 4
                if (cn < 56) out0[(long)row*56 + cn] = v;
                if (cn < 32) outb0[(long)row*32 + cn] = f2us(cn < DTR ? v : 0.f);
            }
        }
    }
}

// ---------------- depthwise causal conv + silu -> bf16 ---------------------------
__global__ __launch_bounds__(256) void conv_kernel(
        const ushort_t* __restrict__ xi,
        const float* __restrict__ cw_f, const float* __restrict__ cb_f,
        const float* __restrict__ cw_b, const float* __restrict__ cb_b,
        ushort_t* __restrict__ xcb)
{
    int vidx = blockIdx.x*256 + threadIdx.x;
    if (vidx >= 2*NROWS*192) return;
    int dq = vidx % 192; int d4 = dq*4;
    int r2 = vidx / 192;
    int dir = r2 / NROWS;
    int rr  = r2 % NROWS;
    int b = rr / L_SEQ, p = rr % L_SEQ;
    const float* cw = dir ? cw_b : cw_f;
    const float* cb = dir ? cb_b : cb_f;
    float w[4][4];
    #pragma unroll
    for (int dd = 0; dd < 4; dd++){
        float4 wv = *(const float4*)(cw + (d4+dd)*KCONV);
        w[dd][0]=wv.x; w[dd][1]=wv.y; w[dd][2]=wv.z; w[dd][3]=wv.w;
    }
    float4 acc = *(const float4*)(cb + d4);
    #pragma unroll
    for (int j = 0; j < KCONV; j++){
        int pp = p - (KCONV-1) + j;
        if (pp >= 0){
            int phys = dir ? (L_SEQ-1-pp) : pp;
            ushort4 u = *(const ushort4*)(xi + ((long)b*L_SEQ + phys)*DI + d4);
            acc.x += w[0][j]*us2f(u.x);
            acc.y += w[1][j]*us2f(u.y);
            acc.z += w[2][j]*us2f(u.z);
            acc.w += w[3][j]*us2f(u.w);
        }
    }
    ushort4 ob;
    ob.x = f2us(acc.x/(1.f+__expf(-acc.x)));
    ob.y = f2us(acc.y/(1.f+__expf(-acc.y)));
    ob.z = f2us(acc.z/(1.f+__expf(-acc.z)));
    ob.w = f2us(acc.w/(1.f+__expf(-acc.w)));
    *(ushort4*)(xcb + (long)r2*DI + d4) = ob;
}

// ---------------- chunked selective scan: pass1 (bf16 LDS) ------------------------
__global__ __launch_bounds__(256) void scan_pass1_kernel(
        const ushort_t* __restrict__ xcb, const ushort_t* __restrict__ dtb,
        const float* __restrict__ xdbl2,
        const float* __restrict__ Alog_f, const float* __restrict__ Alog_b,
        float* __restrict__ Pbuf, float* __restrict__ Sbuf)
{
    int dchunk = blockIdx.x;
    int chunk  = blockIdx.y;
    int z      = blockIdx.z;
    int b = z & 1, dir = z >> 1;
    int tid = threadIdx.x;
    int dl = tid >> 2, nq = tid & 3;
    int dbase = dchunk*DTILE;
    int d = dbase + dl;

    const ushort_t* xc = xcb + (long)dir*NROWS*DI;
    const ushort_t* dt = dtb + (long)dir*NROWS*DI;
    const float* xd = xdbl2 + (long)dir*NROWS*56;
    const float* Alog = dir ? Alog_b : Alog_f;

    float Av2[4];
    #pragma unroll
    for (int j = 0; j < 4; j++)
        Av2[j] = -__expf(Alog[d*DS + nq*4 + j]) * LOG2E;

    __shared__ ushort_t sdt[CLEN][DTILE], sxc[CLEN][DTILE];
    __shared__ float sB[CLEN][16];
    int c0 = chunk * CLEN;
    for (int e = tid; e < CLEN*16; e += 256){
        int s = e >> 4, q4 = (e & 15)*4;
        long row = (long)b*L_SEQ + c0 + s;
        *(ushort4*)&sdt[s][q4] = *(const ushort4*)(dt + row*DI + dbase + q4);
        *(ushort4*)&sxc[s][q4] = *(const ushort4*)(xc + row*DI + dbase + q4);
    }
    for (int e = tid; e < CLEN*4; e += 256){
        int s = e >> 2, q4 = (e & 3)*4;
        long row = (long)b*L_SEQ + c0 + s;
        *(float4*)&sB[s][q4] = *(const float4*)(xd + row*56 + DTR + q4);
    }
    __syncthreads();

    float h0=0.f,h1=0.f,h2=0.f,h3=0.f, dts=0.f;
    for (int s = 0; s < CLEN; s++){
        float dtv = us2f(sdt[s][dl]), xcv = us2f(sxc[s][dl]);
        float4 Bv = *(float4*)&sB[s][nq*4];
        float tmp = dtv*xcv;
        dts += dtv;
        h0 = exp2f(dtv*Av2[0])*h0 + tmp*Bv.x;
        h1 = exp2f(dtv*Av2[1])*h1 + tmp*Bv.y;
        h2 = exp2f(dtv*Av2[2])*h2 + tmp*Bv.z;
        h3 = exp2f(dtv*Av2[3])*h3 + tmp*Bv.w;
    }
    long idx = (((long)z*NCHUNK + chunk)*DI + d)*DS + nq*4;
    float4 P; P.x=exp2f(Av2[0]*dts); P.y=exp2f(Av2[1]*dts);
    P.z=exp2f(Av2[2]*dts); P.w=exp2f(Av2[3]*dts);
    float4 S; S.x=h0; S.y=h1; S.z=h2; S.w=h3;
    *(float4*)(Pbuf + idx) = P;
    *(float4*)(Sbuf + idx) = S;
}

// ---------------- combine: grouped prefetch (groups of 7, 49 = 7x7) ---------------
__global__ __launch_bounds__(256) void scan_combine_kernel(
        const float* __restrict__ Pbuf, float* __restrict__ Sbuf)
{
    int gid = blockIdx.x*256 + threadIdx.x;
    if (gid >= 4*DI*DS/4) return;
    int dn4 = (gid % (DI*DS/4))*4;
    int z   = gid / (DI*DS/4);
    long idx = (long)z*NCHUNK*DI*DS + dn4;
    float4 hin = {0.f,0.f,0.f,0.f};
    for (int cg = 0; cg < NCHUNK; cg += 7){
        float4 P[7], S[7];
        #pragma unroll
        for (int j = 0; j < 7; j++){
            P[j] = *(const float4*)(Pbuf + idx + (long)j*DI*DS);
            S[j] = *(const float4*)(Sbuf + idx + (long)j*DI*DS);
        }
        #pragma unroll
        for (int j = 0; j < 7; j++){
            *(float4*)(Sbuf + idx + (long)j*DI*DS) = hin;
            hin.x = P[j].x*hin.x + S[j].x;
            hin.y = P[j].y*hin.y + S[j].y;
            hin.z = P[j].z*hin.z + S[j].z;
            hin.w = P[j].w*hin.w + S[j].w;
        }
        idx += (long)7*DI*DS;
    }
}

// ---------------- pass2 merged: both dirs CONCURRENT (8 waves) + fused ys gate ----
// CLEN=32 -> LDS exactly 32768B -> up to 4 blocks/CU (32-wave cap), 2x the old
// 16-wave occupancy, and the serial recurrence shortens 49->32 steps.
__global__ __launch_bounds__(512) void scan_pass2_kernel(
        const ushort_t* __restrict__ xcb, const ushort_t* __restrict__ dtb,
        const float* __restrict__ xdbl2,
        const float* __restrict__ Alog_f, const float* __restrict__ Dp_f,
        const float* __restrict__ Alog_b, const float* __restrict__ Dp_b,
        const float* __restrict__ Hbuf,
        const ushort_t* __restrict__ zi,
        ushort_t* __restrict__ ys)
{
    int dchunk = blockIdx.x;
    int chunkf = blockIdx.y;
    int b      = blockIdx.z;
    int tid = threadIdx.x;
    int dgrp = tid >> 8;                 // 0 = forward, 1 = backward
    int t2 = tid & 255;
    int dl = t2 >> 2, nq = t2 & 3;
    int dbase = dchunk*DTILE;
    int d = dbase + dl;
    int chunkb = NCHUNK-1-chunkf;
    int c0f = chunkf*CLEN, c0b = chunkb*CLEN;
    int mychunk = dgrp ? chunkb : chunkf;

    const float* Alog = dgrp ? Alog_b : Alog_f;
    const float* Dpp  = dgrp ? Dp_b   : Dp_f;
    float Av[4];
    #pragma unroll
    for (int j = 0; j < 4; j++)
        Av[j] = -__expf(Alog[d*DS + nq*4 + j]) * LOG2E;
    float Dval = Dpp[d];

    __shared__ ushort_t sdt[2][CLEN][DTILE], sxc[2][CLEN][DTILE];
    __shared__ float sB[2][CLEN][16], sC[2][CLEN][16];
    __shared__ ushort_t sy0[CLEN][DTILE], sy1[CLEN][DTILE];

    // stage both directions (all 512 threads)
    for (int e = tid; e < 2*CLEN*16; e += 512){
        int dir = (e >= CLEN*16) ? 1 : 0;
        int e2 = e - dir*CLEN*16;
        int s = e2 >> 4, q4 = (e2 & 15)*4;
        int c0 = dir ? c0b : c0f;
        long row = (long)b*L_SEQ + c0 + s;
        const ushort_t* dt = dtb + (long)dir*NROWS*DI;
        const ushort_t* xc = xcb + (long)dir*NROWS*DI;
        *(ushort4*)&sdt[dir][s][q4] = *(const ushort4*)(dt + row*DI + dbase + q4);
        *(ushort4*)&sxc[dir][s][q4] = *(const ushort4*)(xc + row*DI + dbase + q4);
    }
    for (int e = tid; e < 2*CLEN*4; e += 512){
        int dir = (e >= CLEN*4) ? 1 : 0;
        int e2 = e - dir*CLEN*4;
        int s = e2 >> 2, q4 = (e2 & 3)*4;
        int c0 = dir ? c0b : c0f;
        long row = (long)b*L_SEQ + c0 + s;
        const float* xd = xdbl2 + (long)dir*NROWS*56;
        *(float4*)&sB[dir][s][q4] = *(const float4*)(xd + row*56 + DTR + q4);
        *(float4*)&sC[dir][s][q4] = *(const float4*)(xd + row*56 + DTR + DS + q4);
    }
    __syncthreads();

    // each half-block scans its direction concurrently
    {
        long idx = (((long)(dgrp*2 + b)*NCHUNK + mychunk)*DI + d)*DS + nq*4;
        float4 H = *(const float4*)(Hbuf + idx);
        float h0=H.x, h1=H.y, h2=H.z, h3=H.w;
        for (int s = 0; s < CLEN; s++){
            float dtv = us2f(sdt[dgrp][s][dl]), xcv = us2f(sxc[dgrp][s][dl]);
            float4 Bv = *(float4*)&sB[dgrp][s][nq*4];
            float4 Cv = *(float4*)&sC[dgrp][s][nq*4];
            float tmp = dtv*xcv;
            h0 = exp2f(dtv*Av[0])*h0 + tmp*Bv.x;
            h1 = exp2f(dtv*Av[1])*h1 + tmp*Bv.y;
            h2 = exp2f(dtv*Av[2])*h2 + tmp*Bv.z;
            h3 = exp2f(dtv*Av[3])*h3 + tmp*Bv.w;
            float c = h0*Cv.x + h1*Cv.y + h2*Cv.z + h3*Cv.w;
            c += __shfl_xor(c, 1);
            c += __shfl_xor(c, 2);
            if (nq == 0){
                if (dgrp == 0) sy0[s][dl] = f2us(c + Dval*xcv);
                else           sy1[CLEN-1-s][dl] = f2us(c + Dval*xcv);
            }
        }
    }
    __syncthreads();

    // fused gate epilogue: ys = (yf+yb)*silu(zi), coalesced at phys rows
    for (int e = tid; e < CLEN*16; e += 512){
        int s = e >> 4, q4 = (e & 15)*4;
        long prow = (long)b*L_SEQ + c0f + s;
        ushort4 zv = *(const ushort4*)(zi + prow*DI + dbase + q4);
        ushort4 ya = *(const ushort4*)&sy0[s][q4];
        ushort4 yb = *(const ushort4*)&sy1[s][q4];
        ushort4 o;
        {
            float z0 = us2f(zv.x); o.x = f2us((us2f(ya.x)+us2f(yb.x)) * z0/(1.f+__expf(-z0)));
        }{
            float z1 = us2f(zv.y); o.y = f2us((us2f(ya.y)+us2f(yb.y)) * z1/(1.f+__expf(-z1)));
        }{
            float z2 = us2f(zv.z); o.z = f2us((us2f(ya.z)+us2f(yb.z)) * z2/(1.f+__expf(-z2)));
        }{
            float z3 = us2f(zv.w); o.w = f2us((us2f(ya.w)+us2f(yb.w)) * z3/(1.f+__expf(-z3)));
        }
        *(ushort4*)(ys + prow*DI + dbase + q4) = o;
    }
}

// ---------------- final rmsnorm (read-only res) ----------------------------------
__global__ __launch_bounds__(128) void rmsnorm_final_kernel(
        const float* __restrict__ res,
        const float* __restrict__ w, float* __restrict__ out)
{
    int r = blockIdx.x; int tid = threadIdx.x;
    const float* rr = res + (long)r*DM;
    float v[3]; float ss = 0.f;
    #pragma unroll
    for (int i = 0; i < 3; i++){
        int c = tid + i*128;
        float x = rr[c];
        v[i] = x; ss += x*x;
    }
    #pragma unroll
    for (int off = 32; off; off >>= 1) ss += __shfl_down(ss, off, 64);
    __shared__ float wsum[2];
    if ((tid & 63) == 0) wsum[tid >> 6] = ss;
    __syncthreads();
    float scale = rsqrtf((wsum[0] + wsum[1]) / (float)DM + EPS_);
    #pragma unroll
    for (int i = 0; i < 3; i++){
        int c = tid + i*128;
        out[(long)r*DM + c] = v[i] * scale * w[c];
    }
}

extern "C" void kernel_launch(void* const* d_in, const int* in_sizes, int n_in,
                              void* d_out, int out_size, void* d_ws, size_t ws_size,
                              hipStream_t stream)
{
    const float* x         = (const float*)d_in[0];
    const float* patch_w   = (const float*)d_in[1];
    const float* patch_b   = (const float*)d_in[2];
    const float* pos_embed = (const float*)d_in[3];
    const float* temp_pos  = (const float*)d_in[4];
    const float* in_proj   = (const float*)d_in[5];
    const float* conv_w    = (const float*)d_in[6];
    const float* conv_b    = (const float*)d_in[7];
    const float* xproj_w   = (const float*)d_in[8];
    const float* dt_w      = (const float*)d_in[9];
    const float* dt_b      = (const float*)d_in[10];
    const float* A_log     = (const float*)d_in[11];
    const float* Dp        = (const float*)d_in[12];
    const float* conv_w_b  = (const float*)d_in[13];
    const float* conv_b_b  = (const float*)d_in[14];
    const float* xproj_w_b = (const float*)d_in[15];
    const float* dt_w_b    = (const float*)d_in[16];
    const float* dt_b_b    = (const float*)d_in[17];
    const float* A_log_b   = (const float*)d_in[18];
    const float* Dp_b      = (const float*)d_in[19];
    const float* out_proj  = (const float*)d_in[20];
    const float* norm_w    = (const float*)d_in[21];
    const float* norm_f    = (const float*)d_in[22];

    float* ws = (float*)d_ws;
    size_t off = 0;
    // Pbuf span: pbufhead + xi + ysf + ysb = 4*602112 = 2,408,448 floats
    //          = exactly 4*NCHUNK*DI*DS (NCHUNK=49). All four dead by pass1 time.
    float* residual = ws + off; off += (size_t)NROWS*DM;           // 1,204,224
    float* pbufhead = ws + off; off += (size_t)NROWS*DM/2;         // 602,112 (free)
    float* xireg    = ws + off; off += (size_t)NROWS*DI/2;         // bf16 xi
    float* ysfreg   = ws + off; off += (size_t)NROWS*DI/2;         // (Pbuf span)
    float* ysbreg   = ws + off; off += (size_t)NROWS*DI/2;         // (Pbuf span)
    float* zireg    = ws + off; off += (size_t)NROWS*DI/2;         // bf16 zi; ys alias
    float* xc2bfreg = ws + off; off += (size_t)NROWS*DI;           // bf16 xc, 2 dirs
    float* xdbl2    = ws + off; off += (size_t)2*NROWS*56;
    float* xdblbf_f = ws + off; off += (size_t)2*NROWS*32/2;
    float* dt2bfreg = ws + off; off += (size_t)NROWS*DI;           // bf16 dt; patches alias
    float* Sbuf     = ws + off; off += (size_t)4*NCHUNK*DI*DS;     // 2,408,448
    float* wpbf_f   = ws + off; off += (size_t)(DM*DI+1)/2;
    size_t fixed_floats = off;
    const size_t perW = (size_t)(WCVT_TOTAL+1)/2;
    int G = (ws_size/4 >= fixed_floats + 24*perW) ? 24
          : (ws_size/4 >= fixed_floats + 8*perW)  ? 8 : 1;
    float* wbf_f = ws + off; off += G*perW;

    ushort_t* xi_bf      = (ushort_t*)xireg;
    ushort_t* zi_bf      = (ushort_t*)zireg;
    ushort_t* ys_bf      = (ushort_t*)zireg;   // pass2 reads zi[i] then writes ys[i]: safe
    ushort_t* xc2_bf     = (ushort_t*)xc2bfreg;
    ushort_t* xdbl_bf    = (ushort_t*)xdblbf_f;
    ushort_t* dt2_bf     = (ushort_t*)dt2bfreg;
    ushort_t* patches_bf = (ushort_t*)dt2bfreg;  // dead before dt GEMM of layer 0
    ushort_t* wbuf       = (ushort_t*)wbf_f;
    ushort_t* wp_bf      = (ushort_t*)wpbf_f;
    float* Pbuf = pbufhead;   // spans pbufhead,xi,ysf,ysb (contiguous, exact fit)
    (void)ysfreg; (void)ysbreg;

    patchify_kernel<<<(NROWS*768/4+255)/256, 256, 0, stream>>>(x, patches_bf);
    convert_kernel<<<(DM*DI+255)/256, 256, 0, stream>>>(patch_w, wp_bf, DM*DI);
    gemm_mfma_kernel<4,1,0><<<dim3(DM/64, NROWS/64, 1), 256, 0, stream>>>(
        patches_bf, DI, 0, wp_bf, DI, 0, DI, DM,
        residual, 0, nullptr, nullptr, 0, 2, patch_b, pos_embed, temp_pos);

    for (int l = 0; l < DEPTH; l++){
        if (l % G == 0){
            int cnt = (DEPTH - l < G) ? DEPTH - l : G;
            long total = (long)cnt*WCVT_Q;
            convert_group_kernel<<<(int)((total+255)/256), 256, 0, stream>>>(
                in_proj, out_proj, xproj_w, xproj_w_b, dt_w, dt_w_b, norm_w,
                wbuf, l, cnt);
        }
        ushort_t* wl = wbuf + (size_t)(l % G)*WCVT_TOTAL;
        ushort_t* wi_bf  = wl;
        ushort_t* wo_bf  = wl + WI_SZ;
        ushort_t* wx_bf  = wl + WI_SZ + WO_SZ;
        ushort_t* wdt_bf = wl + WI_SZ + WO_SZ + 2*WX_SZ;

        // in_proj with fused rmsnorm: A = residual f32, norm_w folded into wi
        gemm_mfma_kernel<4,1,1><<<dim3(2*DI/64, NROWS/64, 1), 256, 0, stream>>>(
            residual, DM, 0, wi_bf, DM, 0, DM, 2*DI,
            nullptr, 0, xi_bf, zi_bf, 0, 1, nullptr, nullptr, nullptr);

        conv_kernel<<<(2*NROWS*192+255)/256, 256, 0, stream>>>(
            xi_bf, conv_w + (size_t)l*DI*KCONV, conv_b + (size_t)l*DI,
            conv_w_b + (size_t)l*DI*KCONV, conv_b_b + (size_t)l*DI, xc2_bf);

        gemm_mfma_kernel<1,1,0><<<dim3(1, NROWS/16, 2), 256, 0, stream>>>(
            xc2_bf, DI, (long)NROWS*DI, wx_bf, DI, WX_SZ, DI, 64,
            xdbl2, (long)NROWS*56, xdbl_bf, nullptr, (long)NROWS*32, 4,
            nullptr, nullptr, nullptr);

        gemm_mfma_kernel<4,0,0><<<dim3(DI/64, NROWS/64, 2), 256, 0, stream>>>(
            xdbl_bf, 32, (long)NROWS*32, wdt_bf, 32, WDT_SZ, 32, DI,
            nullptr, 0, dt2_bf, nullptr, (long)NROWS*DI, 3,
            dt_b + (size_t)l*DI, dt_b_b + (size_t)l*DI, nullptr);

        scan_pass1_kernel<<<dim3(NDC, NCHUNK, 4), 256, 0, stream>>>(
            xc2_bf, dt2_bf, xdbl2, A_log + (size_t)l*DI*DS, A_log_b + (size_t)l*DI*DS,
            Pbuf, Sbuf);
        scan_combine_kernel<<<(4*DI*DS/4+255)/256, 256, 0, stream>>>(Pbuf, Sbuf);
        scan_pass2_kernel<<<dim3(NDC, NCHUNK, BATCH), 512, 0, stream>>>(
            xc2_bf, dt2_bf, xdbl2,
            A_log + (size_t)l*DI*DS, Dp + (size_t)l*DI,
            A_log_b + (size_t)l*DI*DS, Dp_b + (size_t)l*DI,
            Sbuf, zi_bf, ys_bf);

        gemm_mfma_kernel<4,1,0><<<dim3(DM/64, NROWS/64, 1), 256, 0, stream>>>(
            ys_bf, DI, 0, wo_bf, DI, 0, DI, DM,
            residual, 0, nullptr, nullptr, 0, 0, nullptr, nullptr, nullptr);
    }

    rmsnorm_final_kernel<<<NROWS, 128, 0, stream>>>(residual, norm_f, (float*)d_out);
}

// Round 10
// 3664.208 us; speedup vs baseline: 1.1647x; 1.1647x over previous
//
#include <hip/hip_runtime.h>
#include <hip/hip_bf16.h>

typedef unsigned short ushort_t;
typedef short bf16x8 __attribute__((ext_vector_type(8)));
typedef unsigned short us16x8 __attribute__((ext_vector_type(8)));
typedef float f32x4  __attribute__((ext_vector_type(4)));

#define BATCH   2
#define FRAMES  8
#define GRID_   14
#define NTOK    196
#define PS      16
#define IMG     224
#define L_SEQ   1568
#define DM      384
#define DI      768
#define DTR     24
#define DS      16
#define DEPTH   24
#define KCONV   4
#define NROWS   (BATCH*L_SEQ)   // 3136
#define EPS_    1e-5f
#define NCHUNK  32
#define CLEN    49              // 32*49 = 1568
#define DTILE   64
#define NDC     (DI/DTILE)      // 12
#define LOG2E   1.4426950408889634f

__device__ __forceinline__ ushort_t f2us(float f){
    __hip_bfloat16 h = __float2bfloat16(f);
    return *reinterpret_cast<ushort_t*>(&h);
}
__device__ __forceinline__ float us2f(ushort_t u){
    return __uint_as_float(((unsigned int)u) << 16);
}
__device__ __forceinline__ ushort4 f4tous4(float4 v){
    ushort4 o;
    o.x = f2us(v.x); o.y = f2us(v.y); o.z = f2us(v.z); o.w = f2us(v.w);
    return o;
}

// ---------------- patchify (4 px per thread, float4 read) -------------------------
__global__ __launch_bounds__(256) void patchify_kernel(const float* __restrict__ x,
                                                       ushort_t* __restrict__ patches){
    int idx4 = blockIdx.x*256 + threadIdx.x;
    if (idx4 >= NROWS*768/4) return;
    int idx = idx4*4;
    int k   = idx % 768;
    int r   = idx / 768;
    int tok = r % NTOK;
    int bt  = r / NTOK;
    int t = bt % FRAMES, b = bt / FRAMES;
    int gy = tok / GRID_, gx = tok % GRID_;
    int c = k / 256; int rem = k % 256; int py = rem/16, px = rem%16; // px 4-aligned
    long xo = (((long)(b*3 + c)*FRAMES + t)*IMG + (gy*PS+py))*IMG + (gx*PS+px);
    float4 v = *(const float4*)(x + xo);
    *(ushort4*)(patches + idx) = f4tous4(v);
}

__global__ __launch_bounds__(256) void convert_kernel(const float* __restrict__ in,
                                                      ushort_t* __restrict__ out, int n){
    int i = blockIdx.x*256 + threadIdx.x;
    if (i < n) out[i] = f2us(in[i]);
}

// ---------------- grouped weight conversion (4-wide, norm_w folded into wi) -------
#define WI_SZ  (2*DI*DM)
#define WO_SZ  (DM*DI)
#define WX_SZ  (56*DI)
#define WDT_SZ (DI*32)
#define WCVT_TOTAL (WI_SZ + WO_SZ + 2*WX_SZ + 2*WDT_SZ)   // 1,019,904
#define WCVT_Q  (WCVT_TOTAL/4)                            // 254,976

__global__ __launch_bounds__(256) void convert_group_kernel(
        const float* __restrict__ wi, const float* __restrict__ wo,
        const float* __restrict__ wxf, const float* __restrict__ wxb,
        const float* __restrict__ wdtf, const float* __restrict__ wdtb,
        const float* __restrict__ nw,
        ushort_t* __restrict__ out, int l0, int count)
{
    long gid = (long)blockIdx.x*256 + threadIdx.x;
    if (gid >= (long)count*WCVT_Q) return;
    int ly = (int)(gid / WCVT_Q);
    int r  = (int)(gid % WCVT_Q)*4;
    int l  = l0 + ly;
    float4 v;
    if (r < WI_SZ){
        v = *(const float4*)(wi + (long)l*WI_SZ + r);
        int c = r % DM;                       // DM%4==0 -> no row crossing
        float4 wv = *(const float4*)(nw + (long)l*DM + c);
        v.x *= wv.x; v.y *= wv.y; v.z *= wv.z; v.w *= wv.w;
    }
    else if (r < WI_SZ+WO_SZ)            v = *(const float4*)(wo + (long)l*WO_SZ + r - WI_SZ);
    else if (r < WI_SZ+WO_SZ+WX_SZ)      v = *(const float4*)(wxf + (long)l*WX_SZ + r - WI_SZ - WO_SZ);
    else if (r < WI_SZ+WO_SZ+2*WX_SZ)    v = *(const float4*)(wxb + (long)l*WX_SZ + r - WI_SZ - WO_SZ - WX_SZ);
    else if (r < WI_SZ+WO_SZ+2*WX_SZ+WDT_SZ){
        int i = r - (WI_SZ+WO_SZ+2*WX_SZ);
        int rr = i >> 5, c = i & 31;           // c 4-aligned; pad boundary 24 is 4-aligned
        v = (c < DTR) ? *(const float4*)(wdtf + (long)l*DI*DTR + rr*DTR + c)
                      : float4{0.f,0.f,0.f,0.f};
    } else {
        int i = r - (WI_SZ+WO_SZ+2*WX_SZ+WDT_SZ);
        int rr = i >> 5, c = i & 31;
        v = (c < DTR) ? *(const float4*)(wdtb + (long)l*DI*DTR + rr*DTR + c)
                      : float4{0.f,0.f,0.f,0.f};
    }
    *(ushort4*)(out + (long)ly*WCVT_TOTAL + r) = f4tous4(v);
}

// ---------------- MFMA GEMM: C[M,N] = A[M,K] * W[N,K]^T --------------------------
// STAGE=1: A-tile staged through double-buffered LDS (shared by 4 waves).
// NORM=1: A is f32 (residual); stager computes per-row rsqrt(mean(x^2)+eps) and
//         the epilogue multiplies by it (norm_w is pre-folded into W).
// modes: 0 out_proj -> res +=; 1 in_proj split -> bf16 xi/zi; 2 patch -> res=v+aux;
//        4 xproj dual (f32 56 + bf16 32 pad0)
template<int MT, int STAGE, int NORM>
__global__ __launch_bounds__(256) void gemm_mfma_kernel(
        const void* __restrict__ Av_, int lda, long strideA,
        const ushort_t* __restrict__ W, int ldw, long strideW,
        int K, int N,
        float* __restrict__ out0, long strideO0,
        ushort_t* __restrict__ outb0, ushort_t* __restrict__ outb1, long strideOb,
        int mode,
        const float* __restrict__ aux0, const float* __restrict__ aux1,
        const float* __restrict__ aux2)
{
    int z = blockIdx.z;
    W += (long)z * strideW;
    if (out0)  out0  += (long)z * strideO0;
    if (outb0) outb0 += (long)z * strideOb;

    int tid  = threadIdx.x;
    int wave = tid >> 6, lane = tid & 63;
    int l15 = lane & 15, quad = lane >> 4;
    int m0 = blockIdx.y * (MT*16), n0 = blockIdx.x * 64;

    const ushort_t* wp = W + (long)(n0 + wave*16 + l15)*ldw + quad*8;

    f32x4 acc[MT];
    #pragma unroll
    for (int mt = 0; mt < MT; mt++) acc[mt] = f32x4{0,0,0,0};

    __shared__ float sscale[MT*16];

    if constexpr (STAGE){
        __shared__ alignas(16) ushort_t As[2][MT*16][40];
        bool act = (tid < MT*64);
        int srow = tid >> 2, skq = tid & 3;
        int nIter = K >> 5;
        float ss = 0.f;
        us16x8 av = {};
        const ushort_t* ag = nullptr;
        const float*    agf = nullptr;
        if constexpr (NORM){
            agf = (const float*)Av_ + (long)z*strideA + (long)(m0 + srow)*lda + skq*8;
            float4 a0 = *(const float4*)agf;
            float4 a1 = *(const float4*)(agf + 4);
            ss += a0.x*a0.x + a0.y*a0.y + a0.z*a0.z + a0.w*a0.w
                + a1.x*a1.x + a1.y*a1.y + a1.z*a1.z + a1.w*a1.w;
            av[0]=(short)f2us(a0.x); av[1]=(short)f2us(a0.y); av[2]=(short)f2us(a0.z); av[3]=(short)f2us(a0.w);
            av[4]=(short)f2us(a1.x); av[5]=(short)f2us(a1.y); av[6]=(short)f2us(a1.z); av[7]=(short)f2us(a1.w);
        } else {
            ag = (const ushort_t*)Av_ + (long)z*strideA + (long)(m0 + srow)*lda + skq*8;
            if (act) av = *(const us16x8*)ag;
        }
        for (int it = 0; it < nIter; it++){
            if (act) *(us16x8*)&As[it&1][srow][skq*8] = av;
            if (it+1 < nIter){
                if constexpr (NORM){
                    float4 a0 = *(const float4*)(agf + (long)(it+1)*32);
                    float4 a1 = *(const float4*)(agf + (long)(it+1)*32 + 4);
                    ss += a0.x*a0.x + a0.y*a0.y + a0.z*a0.z + a0.w*a0.w
                        + a1.x*a1.x + a1.y*a1.y + a1.z*a1.z + a1.w*a1.w;
                    av[0]=(short)f2us(a0.x); av[1]=(short)f2us(a0.y); av[2]=(short)f2us(a0.z); av[3]=(short)f2us(a0.w);
                    av[4]=(short)f2us(a1.x); av[5]=(short)f2us(a1.y); av[6]=(short)f2us(a1.z); av[7]=(short)f2us(a1.w);
                } else {
                    if (act) av = *(const us16x8*)(ag + (long)(it+1)*32);
                }
            }
            __syncthreads();
            bf16x8 bfrag = *reinterpret_cast<const bf16x8*>(wp + it*32);
            #pragma unroll
            for (int mt = 0; mt < MT; mt++){
                bf16x8 afrag = *reinterpret_cast<const bf16x8*>(&As[it&1][mt*16+l15][quad*8]);
                acc[mt] = __builtin_amdgcn_mfma_f32_16x16x32_bf16(afrag, bfrag, acc[mt], 0, 0, 0);
            }
        }
        if constexpr (NORM){
            ss += __shfl_xor(ss, 1);
            ss += __shfl_xor(ss, 2);
            if (skq == 0) sscale[srow] = rsqrtf(ss/(float)K + EPS_);
            __syncthreads();
        }
    } else {
        const ushort_t* ap0 = (const ushort_t*)Av_ + (long)z*strideA + (long)(m0 + l15)*lda + quad*8;
        for (int k0 = 0; k0 < K; k0 += 32){
            bf16x8 bfrag = *reinterpret_cast<const bf16x8*>(wp + k0);
            #pragma unroll
            for (int mt = 0; mt < MT; mt++){
                bf16x8 afrag = *reinterpret_cast<const bf16x8*>(ap0 + (long)mt*16*lda + k0);
                acc[mt] = __builtin_amdgcn_mfma_f32_16x16x32_bf16(afrag, bfrag, acc[mt], 0, 0, 0);
            }
        }
    }

    int cn = n0 + wave*16 + l15;
    #pragma unroll
    for (int mt = 0; mt < MT; mt++){
        #pragma unroll
        for (int r = 0; r < 4; r++){
            int lrow = mt*16 + quad*4 + r;
            int row = m0 + lrow;
            float v = acc[mt][r];
            if constexpr (NORM){ v *= sscale[lrow]; }
            if (mode == 0){
                out0[(long)row*N + cn] += v;
            } else if (mode == 1){
                if (cn < DI) outb0[(long)row*DI + cn] = f2us(v);
                else         outb1[(long)row*DI + cn - DI] = f2us(v);
            } else if (mode == 2){
                int tok = row % NTOK, t = (row/NTOK) % FRAMES;
                out0[(long)row*N + cn] = v + aux0[cn] + aux1[tok*DM+cn] + aux2[t*DM+cn];
            } else { // mode 4
                if (cn < 56) out0[(long)row*56 + cn] = v;
                if (cn < 32) outb0[(long)row*32 + cn] = f2us(cn < DTR ? v : 0.f);
            }
        }
    }
}

// ---------------- dedicated dt GEMM: K=32, fast softplus, coalesced stores --------
// dt[row,n] = softplus( xdbl[row,:32] . wdt[n,:32] + bias[n] )
// Epilogue bounces acc through LDS so stores are row-major ushort8 (16B, coalesced)
// instead of scattered 2B; softplus uses native exp2/log (no software log1pf).
__global__ __launch_bounds__(256) void dt_gemm_kernel(
        const ushort_t* __restrict__ A,      // [2][NROWS][32] bf16
        const ushort_t* __restrict__ W,      // [2][DI][32] bf16 (cols>=24 zero)
        const float* __restrict__ dtb_f, const float* __restrict__ dtb_b,
        ushort_t* __restrict__ dt2)          // [2][NROWS][DI] bf16
{
    int z = blockIdx.z;
    const ushort_t* Az = A + (long)z*NROWS*32;
    const ushort_t* Wz = W + (long)z*WDT_SZ;
    const float* dtb = z ? dtb_b : dtb_f;
    int tid = threadIdx.x;
    int wave = tid >> 6, lane = tid & 63;
    int l15 = lane & 15, quad = lane >> 4;
    int m0 = blockIdx.y*64, n0 = blockIdx.x*64;
    int cn = n0 + wave*16 + l15;

    bf16x8 bfrag = *reinterpret_cast<const bf16x8*>(Wz + (long)cn*32 + quad*8);
    float bias = dtb[cn];
    const ushort_t* ap0 = Az + (long)(m0 + l15)*32 + quad*8;
    f32x4 acc[4];
    #pragma unroll
    for (int mt = 0; mt < 4; mt++){
        bf16x8 afrag = *reinterpret_cast<const bf16x8*>(ap0 + mt*16*32);
        acc[mt] = __builtin_amdgcn_mfma_f32_16x16x32_bf16(afrag, bfrag, f32x4{0,0,0,0}, 0, 0, 0);
    }

    __shared__ float sc[64][68];   // 68-pad: 16B-aligned rows, 2-way bank alias (free)
    #pragma unroll
    for (int mt = 0; mt < 4; mt++){
        #pragma unroll
        for (int r = 0; r < 4; r++){
            float xs = acc[mt][r] + bias;
            float sp = (xs > 80.f) ? xs : __logf(1.f + exp2f(xs * LOG2E));
            sc[mt*16 + quad*4 + r][wave*16 + l15] = sp;
        }
    }
    __syncthreads();

    ushort_t* dtp = dt2 + (long)z*NROWS*DI;
    for (int e = tid; e < 64*8; e += 256){
        int s = e >> 3, c8 = (e & 7)*8;
        float4 v0 = *(const float4*)&sc[s][c8];
        float4 v1 = *(const float4*)&sc[s][c8+4];
        us16x8 o;
        o[0] = (short)f2us(v0.x); o[1] = (short)f2us(v0.y);
        o[2] = (short)f2us(v0.z); o[3] = (short)f2us(v0.w);
        o[4] = (short)f2us(v1.x); o[5] = (short)f2us(v1.y);
        o[6] = (short)f2us(v1.z); o[7] = (short)f2us(v1.w);
        *(us16x8*)(dtp + (long)(m0+s)*DI + n0 + c8) = o;
    }
}

// ---------------- depthwise causal conv + silu -> bf16 ---------------------------
__global__ __launch_bounds__(256) void conv_kernel(
        const ushort_t* __restrict__ xi,
        const float* __restrict__ cw_f, const float* __restrict__ cb_f,
        const float* __restrict__ cw_b, const float* __restrict__ cb_b,
        ushort_t* __restrict__ xcb)
{
    int vidx = blockIdx.x*256 + threadIdx.x;
    if (vidx >= 2*NROWS*192) return;
    int dq = vidx % 192; int d4 = dq*4;
    int r2 = vidx / 192;
    int dir = r2 / NROWS;
    int rr  = r2 % NROWS;
    int b = rr / L_SEQ, p = rr % L_SEQ;
    const float* cw = dir ? cw_b : cw_f;
    const float* cb = dir ? cb_b : cb_f;
    float w[4][4];
    #pragma unroll
    for (int dd = 0; dd < 4; dd++){
        float4 wv = *(const float4*)(cw + (d4+dd)*KCONV);
        w[dd][0]=wv.x; w[dd][1]=wv.y; w[dd][2]=wv.z; w[dd][3]=wv.w;
    }
    float4 acc = *(const float4*)(cb + d4);
    #pragma unroll
    for (int j = 0; j < KCONV; j++){
        int pp = p - (KCONV-1) + j;
        if (pp >= 0){
            int phys = dir ? (L_SEQ-1-pp) : pp;
            ushort4 u = *(const ushort4*)(xi + ((long)b*L_SEQ + phys)*DI + d4);
            acc.x += w[0][j]*us2f(u.x);
            acc.y += w[1][j]*us2f(u.y);
            acc.z += w[2][j]*us2f(u.z);
            acc.w += w[3][j]*us2f(u.w);
        }
    }
    ushort4 ob;
    ob.x = f2us(acc.x/(1.f+__expf(-acc.x)));
    ob.y = f2us(acc.y/(1.f+__expf(-acc.y)));
    ob.z = f2us(acc.z/(1.f+__expf(-acc.z)));
    ob.w = f2us(acc.w/(1.f+__expf(-acc.w)));
    *(ushort4*)(xcb + (long)r2*DI + d4) = ob;
}

// ---------------- chunked selective scan: pass1 (bf16 LDS) ------------------------
__global__ __launch_bounds__(256) void scan_pass1_kernel(
        const ushort_t* __restrict__ xcb, const ushort_t* __restrict__ dtb,
        const float* __restrict__ xdbl2,
        const float* __restrict__ Alog_f, const float* __restrict__ Alog_b,
        float* __restrict__ Pbuf, float* __restrict__ Sbuf)
{
    int dchunk = blockIdx.x;
    int chunk  = blockIdx.y;
    int z      = blockIdx.z;
    int b = z & 1, dir = z >> 1;
    int tid = threadIdx.x;
    int dl = tid >> 2, nq = tid & 3;
    int dbase = dchunk*DTILE;
    int d = dbase + dl;

    const ushort_t* xc = xcb + (long)dir*NROWS*DI;
    const ushort_t* dt = dtb + (long)dir*NROWS*DI;
    const float* xd = xdbl2 + (long)dir*NROWS*56;
    const float* Alog = dir ? Alog_b : Alog_f;

    float Av2[4];
    #pragma unroll
    for (int j = 0; j < 4; j++)
        Av2[j] = -__expf(Alog[d*DS + nq*4 + j]) * LOG2E;

    __shared__ ushort_t sdt[CLEN][DTILE], sxc[CLEN][DTILE];
    __shared__ float sB[CLEN][16];
    int c0 = chunk * CLEN;
    for (int e = tid; e < CLEN*16; e += 256){
        int s = e >> 4, q4 = (e & 15)*4;
        long row = (long)b*L_SEQ + c0 + s;
        *(ushort4*)&sdt[s][q4] = *(const ushort4*)(dt + row*DI + dbase + q4);
        *(ushort4*)&sxc[s][q4] = *(const ushort4*)(xc + row*DI + dbase + q4);
    }
    for (int e = tid; e < CLEN*4; e += 256){
        int s = e >> 2, q4 = (e & 3)*4;
        long row = (long)b*L_SEQ + c0 + s;
        *(float4*)&sB[s][q4] = *(const float4*)(xd + row*56 + DTR + q4);
    }
    __syncthreads();

    float h0=0.f,h1=0.f,h2=0.f,h3=0.f, dts=0.f;
    for (int s = 0; s < CLEN; s++){
        float dtv = us2f(sdt[s][dl]), xcv = us2f(sxc[s][dl]);
        float4 Bv = *(float4*)&sB[s][nq*4];
        float tmp = dtv*xcv;
        dts += dtv;
        h0 = exp2f(dtv*Av2[0])*h0 + tmp*Bv.x;
        h1 = exp2f(dtv*Av2[1])*h1 + tmp*Bv.y;
        h2 = exp2f(dtv*Av2[2])*h2 + tmp*Bv.z;
        h3 = exp2f(dtv*Av2[3])*h3 + tmp*Bv.w;
    }
    long idx = (((long)z*NCHUNK + chunk)*DI + d)*DS + nq*4;
    float4 P; P.x=exp2f(Av2[0]*dts); P.y=exp2f(Av2[1]*dts);
    P.z=exp2f(Av2[2]*dts); P.w=exp2f(Av2[3]*dts);
    float4 S; S.x=h0; S.y=h1; S.z=h2; S.w=h3;
    *(float4*)(Pbuf + idx) = P;
    *(float4*)(Sbuf + idx) = S;
}

// ---------------- combine: grouped prefetch ---------------------------------------
__global__ __launch_bounds__(256) void scan_combine_kernel(
        const float* __restrict__ Pbuf, float* __restrict__ Sbuf)
{
    int gid = blockIdx.x*256 + threadIdx.x;
    if (gid >= 4*DI*DS/4) return;
    int dn4 = (gid % (DI*DS/4))*4;
    int z   = gid / (DI*DS/4);
    long idx = (long)z*NCHUNK*DI*DS + dn4;
    float4 hin = {0.f,0.f,0.f,0.f};
    for (int cg = 0; cg < NCHUNK; cg += 8){
        float4 P[8], S[8];
        #pragma unroll
        for (int j = 0; j < 8; j++){
            P[j] = *(const float4*)(Pbuf + idx + (long)j*DI*DS);
            S[j] = *(const float4*)(Sbuf + idx + (long)j*DI*DS);
        }
        #pragma unroll
        for (int j = 0; j < 8; j++){
            *(float4*)(Sbuf + idx + (long)j*DI*DS) = hin;
            hin.x = P[j].x*hin.x + S[j].x;
            hin.y = P[j].y*hin.y + S[j].y;
            hin.z = P[j].z*hin.z + S[j].z;
            hin.w = P[j].w*hin.w + S[j].w;
        }
        idx += (long)8*DI*DS;
    }
}

// ---------------- pass2 merged: both dirs CONCURRENT (8 waves) + fused ys gate ----
__global__ __launch_bounds__(512) void scan_pass2_kernel(
        const ushort_t* __restrict__ xcb, const ushort_t* __restrict__ dtb,
        const float* __restrict__ xdbl2,
        const float* __restrict__ Alog_f, const float* __restrict__ Dp_f,
        const float* __restrict__ Alog_b, const float* __restrict__ Dp_b,
        const float* __restrict__ Hbuf,
        const ushort_t* __restrict__ zi,
        ushort_t* __restrict__ ys)
{
    int dchunk = blockIdx.x;
    int chunkf = blockIdx.y;
    int b      = blockIdx.z;
    int tid = threadIdx.x;
    int dgrp = tid >> 8;                 // 0 = forward, 1 = backward
    int t2 = tid & 255;
    int dl = t2 >> 2, nq = t2 & 3;
    int dbase = dchunk*DTILE;
    int d = dbase + dl;
    int chunkb = NCHUNK-1-chunkf;
    int c0f = chunkf*CLEN, c0b = chunkb*CLEN;
    int mychunk = dgrp ? chunkb : chunkf;

    const float* Alog = dgrp ? Alog_b : Alog_f;
    const float* Dpp  = dgrp ? Dp_b   : Dp_f;
    float Av[4];
    #pragma unroll
    for (int j = 0; j < 4; j++)
        Av[j] = -__expf(Alog[d*DS + nq*4 + j]) * LOG2E;
    float Dval = Dpp[d];

    __shared__ ushort_t sdt[2][CLEN][DTILE], sxc[2][CLEN][DTILE];
    __shared__ float sB[2][CLEN][16], sC[2][CLEN][16];
    __shared__ ushort_t sy0[CLEN][DTILE], sy1[CLEN][DTILE];

    // stage both directions (all 512 threads)
    for (int e = tid; e < 2*CLEN*16; e += 512){
        int dir = (e >= CLEN*16) ? 1 : 0;
        int e2 = e - dir*CLEN*16;
        int s = e2 >> 4, q4 = (e2 & 15)*4;
        int c0 = dir ? c0b : c0f;
        long row = (long)b*L_SEQ + c0 + s;
        const ushort_t* dt = dtb + (long)dir*NROWS*DI;
        const ushort_t* xc = xcb + (long)dir*NROWS*DI;
        *(ushort4*)&sdt[dir][s][q4] = *(const ushort4*)(dt + row*DI + dbase + q4);
        *(ushort4*)&sxc[dir][s][q4] = *(const ushort4*)(xc + row*DI + dbase + q4);
    }
    for (int e = tid; e < 2*CLEN*4; e += 512){
        int dir = (e >= CLEN*4) ? 1 : 0;
        int e2 = e - dir*CLEN*4;
        int s = e2 >> 2, q4 = (e2 & 3)*4;
        int c0 = dir ? c0b : c0f;
        long row = (long)b*L_SEQ + c0 + s;
        const float* xd = xdbl2 + (long)dir*NROWS*56;
        *(float4*)&sB[dir][s][q4] = *(const float4*)(xd + row*56 + DTR + q4);
        *(float4*)&sC[dir][s][q4] = *(const float4*)(xd + row*56 + DTR + DS + q4);
    }
    __syncthreads();

    // each half-block scans its direction concurrently
    {
        long idx = (((long)(dgrp*2 + b)*NCHUNK + mychunk)*DI + d)*DS + nq*4;
        float4 H = *(const float4*)(Hbuf + idx);
        float h0=H.x, h1=H.y, h2=H.z, h3=H.w;
        for (int s = 0; s < CLEN; s++){
            float dtv = us2f(sdt[dgrp][s][dl]), xcv = us2f(sxc[dgrp][s][dl]);
            float4 Bv = *(float4*)&sB[dgrp][s][nq*4];
            float4 Cv = *(float4*)&sC[dgrp][s][nq*4];
            float tmp = dtv*xcv;
            h0 = exp2f(dtv*Av[0])*h0 + tmp*Bv.x;
            h1 = exp2f(dtv*Av[1])*h1 + tmp*Bv.y;
            h2 = exp2f(dtv*Av[2])*h2 + tmp*Bv.z;
            h3 = exp2f(dtv*Av[3])*h3 + tmp*Bv.w;
            float c = h0*Cv.x + h1*Cv.y + h2*Cv.z + h3*Cv.w;
            c += __shfl_xor(c, 1);
            c += __shfl_xor(c, 2);
            if (nq == 0){
                if (dgrp == 0) sy0[s][dl] = f2us(c + Dval*xcv);
                else           sy1[CLEN-1-s][dl] = f2us(c + Dval*xcv);
            }
        }
    }
    __syncthreads();

    // fused gate epilogue: ys = (yf+yb)*silu(zi), coalesced at phys rows
    for (int e = tid; e < CLEN*16; e += 512){
        int s = e >> 4, q4 = (e & 15)*4;
        long prow = (long)b*L_SEQ + c0f + s;
        ushort4 zv = *(const ushort4*)(zi + prow*DI + dbase + q4);
        ushort4 ya = *(const ushort4*)&sy0[s][q4];
        ushort4 yb = *(const ushort4*)&sy1[s][q4];
        ushort4 o;
        {
            float z0 = us2f(zv.x); o.x = f2us((us2f(ya.x)+us2f(yb.x)) * z0/(1.f+__expf(-z0)));
        }{
            float z1 = us2f(zv.y); o.y = f2us((us2f(ya.y)+us2f(yb.y)) * z1/(1.f+__expf(-z1)));
        }{
            float z2 = us2f(zv.z); o.z = f2us((us2f(ya.z)+us2f(yb.z)) * z2/(1.f+__expf(-z2)));
        }{
            float z3 = us2f(zv.w); o.w = f2us((us2f(ya.w)+us2f(yb.w)) * z3/(1.f+__expf(-z3)));
        }
        *(ushort4*)(ys + prow*DI + dbase + q4) = o;
    }
}

// ---------------- final rmsnorm (read-only res) ----------------------------------
__global__ __launch_bounds__(128) void rmsnorm_final_kernel(
        const float* __restrict__ res,
        const float* __restrict__ w, float* __restrict__ out)
{
    int r = blockIdx.x; int tid = threadIdx.x;
    const float* rr = res + (long)r*DM;
    float v[3]; float ss = 0.f;
    #pragma unroll
    for (int i = 0; i < 3; i++){
        int c = tid + i*128;
        float x = rr[c];
        v[i] = x; ss += x*x;
    }
    #pragma unroll
    for (int off = 32; off; off >>= 1) ss += __shfl_down(ss, off, 64);
    __shared__ float wsum[2];
    if ((tid & 63) == 0) wsum[tid >> 6] = ss;
    __syncthreads();
    float scale = rsqrtf((wsum[0] + wsum[1]) / (float)DM + EPS_);
    #pragma unroll
    for (int i = 0; i < 3; i++){
        int c = tid + i*128;
        out[(long)r*DM + c] = v[i] * scale * w[c];
    }
}

extern "C" void kernel_launch(void* const* d_in, const int* in_sizes, int n_in,
                              void* d_out, int out_size, void* d_ws, size_t ws_size,
                              hipStream_t stream)
{
    const float* x         = (const float*)d_in[0];
    const float* patch_w   = (const float*)d_in[1];
    const float* patch_b   = (const float*)d_in[2];
    const float* pos_embed = (const float*)d_in[3];
    const float* temp_pos  = (const float*)d_in[4];
    const float* in_proj   = (const float*)d_in[5];
    const float* conv_w    = (const float*)d_in[6];
    const float* conv_b    = (const float*)d_in[7];
    const float* xproj_w   = (const float*)d_in[8];
    const float* dt_w      = (const float*)d_in[9];
    const float* dt_b      = (const float*)d_in[10];
    const float* A_log     = (const float*)d_in[11];
    const float* Dp        = (const float*)d_in[12];
    const float* conv_w_b  = (const float*)d_in[13];
    const float* conv_b_b  = (const float*)d_in[14];
    const float* xproj_w_b = (const float*)d_in[15];
    const float* dt_w_b    = (const float*)d_in[16];
    const float* dt_b_b    = (const float*)d_in[17];
    const float* A_log_b   = (const float*)d_in[18];
    const float* Dp_b      = (const float*)d_in[19];
    const float* out_proj  = (const float*)d_in[20];
    const float* norm_w    = (const float*)d_in[21];
    const float* norm_f    = (const float*)d_in[22];

    float* ws = (float*)d_ws;
    size_t off = 0;
    float* residual = ws + off; off += (size_t)NROWS*DM;           // 1,204,224
    float* hnormreg = ws + off; off += (size_t)NROWS*DM/2;         // Pbuf head
    float* xireg    = ws + off; off += (size_t)NROWS*DI/2;         // bf16 xi; Pbuf tail
    float* zireg    = ws + off; off += (size_t)NROWS*DI/2;         // bf16 zi; ys alias
    float* xc2bfreg = ws + off; off += (size_t)NROWS*DI;           // bf16 xc, 2 dirs
    float* xdbl2    = ws + off; off += (size_t)2*NROWS*56;
    float* xdblbf_f = ws + off; off += (size_t)2*NROWS*32/2;
    float* dt2bfreg = ws + off; off += (size_t)NROWS*DI;           // bf16 dt; patches alias
    float* ysfbfreg = ws + off; off += (size_t)NROWS*DI/2;         // (unused)
    float* ysbbfreg = ws + off; off += (size_t)NROWS*DI/2;         // (unused)
    float* Sbuf     = ws + off; off += (size_t)4*NCHUNK*DI*DS;     // 1,572,864
    float* wpbf_f   = ws + off; off += (size_t)(DM*DI+1)/2;
    size_t fixed_floats = off;
    const size_t perW = (size_t)(WCVT_TOTAL+1)/2;
    int G = (ws_size/4 >= fixed_floats + 24*perW) ? 24
          : (ws_size/4 >= fixed_floats + 8*perW)  ? 8 : 1;
    float* wbf_f = ws + off; off += G*perW;

    ushort_t* xi_bf      = (ushort_t*)xireg;
    ushort_t* zi_bf      = (ushort_t*)zireg;
    ushort_t* ys_bf      = (ushort_t*)zireg;   // pass2 reads zi[i] then writes ys[i]: safe
    ushort_t* xc2_bf     = (ushort_t*)xc2bfreg;
    ushort_t* xdbl_bf    = (ushort_t*)xdblbf_f;
    ushort_t* dt2_bf     = (ushort_t*)dt2bfreg;
    ushort_t* patches_bf = (ushort_t*)dt2bfreg;  // dead before dt GEMM of layer 0
    ushort_t* wbuf       = (ushort_t*)wbf_f;
    ushort_t* wp_bf      = (ushort_t*)wpbf_f;
    float* Pbuf = hnormreg;   // spans hnorm+xi; both dead by pass1
    (void)ysfbfreg; (void)ysbbfreg;

    patchify_kernel<<<(NROWS*768/4+255)/256, 256, 0, stream>>>(x, patches_bf);
    convert_kernel<<<(DM*DI+255)/256, 256, 0, stream>>>(patch_w, wp_bf, DM*DI);
    gemm_mfma_kernel<4,1,0><<<dim3(DM/64, NROWS/64, 1), 256, 0, stream>>>(
        patches_bf, DI, 0, wp_bf, DI, 0, DI, DM,
        residual, 0, nullptr, nullptr, 0, 2, patch_b, pos_embed, temp_pos);

    for (int l = 0; l < DEPTH; l++){
        if (l % G == 0){
            int cnt = (DEPTH - l < G) ? DEPTH - l : G;
            long total = (long)cnt*WCVT_Q;
            convert_group_kernel<<<(int)((total+255)/256), 256, 0, stream>>>(
                in_proj, out_proj, xproj_w, xproj_w_b, dt_w, dt_w_b, norm_w,
                wbuf, l, cnt);
        }
        ushort_t* wl = wbuf + (size_t)(l % G)*WCVT_TOTAL;
        ushort_t* wi_bf  = wl;
        ushort_t* wo_bf  = wl + WI_SZ;
        ushort_t* wx_bf  = wl + WI_SZ + WO_SZ;
        ushort_t* wdt_bf = wl + WI_SZ + WO_SZ + 2*WX_SZ;

        // in_proj with fused rmsnorm: A = residual f32, norm_w folded into wi
        gemm_mfma_kernel<4,1,1><<<dim3(2*DI/64, NROWS/64, 1), 256, 0, stream>>>(
            residual, DM, 0, wi_bf, DM, 0, DM, 2*DI,
            nullptr, 0, xi_bf, zi_bf, 0, 1, nullptr, nullptr, nullptr);

        conv_kernel<<<(2*NROWS*192+255)/256, 256, 0, stream>>>(
            xi_bf, conv_w + (size_t)l*DI*KCONV, conv_b + (size_t)l*DI,
            conv_w_b + (size_t)l*DI*KCONV, conv_b_b + (size_t)l*DI, xc2_bf);

        gemm_mfma_kernel<1,1,0><<<dim3(1, NROWS/16, 2), 256, 0, stream>>>(
            xc2_bf, DI, (long)NROWS*DI, wx_bf, DI, WX_SZ, DI, 64,
            xdbl2, (long)NROWS*56, xdbl_bf, nullptr, (long)NROWS*32, 4,
            nullptr, nullptr, nullptr);

        // dedicated dt GEMM: fast softplus + coalesced ushort8 stores
        dt_gemm_kernel<<<dim3(DI/64, NROWS/64, 2), 256, 0, stream>>>(
            xdbl_bf, wdt_bf, dt_b + (size_t)l*DI, dt_b_b + (size_t)l*DI, dt2_bf);

        scan_pass1_kernel<<<dim3(NDC, NCHUNK, 4), 256, 0, stream>>>(
            xc2_bf, dt2_bf, xdbl2, A_log + (size_t)l*DI*DS, A_log_b + (size_t)l*DI*DS,
            Pbuf, Sbuf);
        scan_combine_kernel<<<(4*DI*DS/4+255)/256, 256, 0, stream>>>(Pbuf, Sbuf);
        scan_pass2_kernel<<<dim3(NDC, NCHUNK, BATCH), 512, 0, stream>>>(
            xc2_bf, dt2_bf, xdbl2,
            A_log + (size_t)l*DI*DS, Dp + (size_t)l*DI,
            A_log_b + (size_t)l*DI*DS, Dp_b + (size_t)l*DI,
            Sbuf, zi_bf, ys_bf);

        gemm_mfma_kernel<4,1,0><<<dim3(DM/64, NROWS/64, 1), 256, 0, stream>>>(
            ys_bf, DI, 0, wo_bf, DI, 0, DI, DM,
            residual, 0, nullptr, nullptr, 0, 0, nullptr, nullptr, nullptr);
    }

    rmsnorm_final_kernel<<<NROWS, 128, 0, stream>>>(residual, norm_f, (float*)d_out);
}